// Round 1
// baseline (110.761 us; speedup 1.0000x reference)
//
#include <hip/hip_runtime.h>
#include <math.h>

#define N_IMG   8
#define C_CH    64
#define H_DIM   512
#define W_DIM   512
#define HW      (H_DIM * W_DIM)          // 262144
#define NTOT    (N_IMG * HW)             // 2097152
#define HW4     (HW / 4)                 // 65536 float4 per image plane
#define EPS_F   1e-8f

// Kernel 1: mean over 64 channels. One thread per 4 consecutive pixels.
__global__ __launch_bounds__(256) void mean64_kernel(const float* __restrict__ x,
                                                     float* __restrict__ m) {
    int o4 = blockIdx.x * blockDim.x + threadIdx.x;   // float4 index, [0, NTOT/4)
    int n  = o4 >> 16;                                // /HW4
    int s4 = o4 & (HW4 - 1);
    const float4* base = reinterpret_cast<const float4*>(x)
                       + (size_t)n * C_CH * HW4 + s4;
    float ax = 0.f, ay = 0.f, az = 0.f, aw = 0.f;
    #pragma unroll
    for (int c = 0; c < C_CH; ++c) {
        float4 v = base[(size_t)c * HW4];
        ax += v.x; ay += v.y; az += v.z; aw += v.w;
    }
    const float inv = 1.0f / 64.0f;
    float4 r; r.x = ax * inv; r.y = ay * inv; r.z = az * inv; r.w = aw * inv;
    reinterpret_cast<float4*>(m)[o4] = r;
}

// Kernel 2: 3x3 clamped stencil + curvature math. One thread per pixel.
__global__ __launch_bounds__(256) void curv_kernel(const float* __restrict__ m,
                                                   const float* __restrict__ alpha_p,
                                                   const float* __restrict__ beta_p,
                                                   float* __restrict__ out) {
    int tid = blockIdx.x * blockDim.x + threadIdx.x;  // [0, NTOT)
    int n = tid >> 18;                                // /HW
    int s = tid & (HW - 1);
    int h = s >> 9;
    int w = s & (W_DIM - 1);
    const float* mp = m + (size_t)n * HW;

    int r0 = (h > 0) ? h - 1 : 0;
    int r2 = (h < H_DIM - 1) ? h + 1 : H_DIM - 1;
    int c0 = (w > 0) ? w - 1 : 0;
    int c2 = (w < W_DIM - 1) ? w + 1 : W_DIM - 1;

    const float* row0 = mp + r0 * W_DIM;
    const float* row1 = mp + h  * W_DIM;
    const float* row2 = mp + r2 * W_DIM;

    float m00 = row0[c0], m01 = row0[w], m02 = row0[c2];
    float m10 = row1[c0], m11 = row1[w], m12 = row1[c2];
    float m20 = row2[c0], m21 = row2[w], m22 = row2[c2];

    // d = [-.5,0,.5], s = [.25,.5,.25], d2 = [1,-2,1]; cross-correlation (no flip)
    float Ix  = 0.5f  * (0.25f * (m02 - m00) + 0.5f * (m12 - m10) + 0.25f * (m22 - m20));
    float Iy  = 0.5f  * (0.25f * (m20 - m00) + 0.5f * (m21 - m01) + 0.25f * (m22 - m02));
    float Ixx = 0.25f * (m00 - 2.0f * m01 + m02)
              + 0.5f  * (m10 - 2.0f * m11 + m12)
              + 0.25f * (m20 - 2.0f * m21 + m22);
    float Iyy = 0.25f * (m00 - 2.0f * m10 + m20)
              + 0.5f  * (m01 - 2.0f * m11 + m21)
              + 0.25f * (m02 - 2.0f * m12 + m22);
    float Ixy = 0.25f * (m00 - m02 - m20 + m22);

    float ix2 = Ix * Ix, iy2 = Iy * Iy;
    float g = 1.0f + ix2 + iy2;
    float K = (Ixx * Iyy - Ixy * Ixy) / (g * g + EPS_F);
    float Hc = ((1.0f + ix2) * Iyy - 2.0f * Ix * Iy * Ixy + (1.0f + iy2) * Ixx)
             / (2.0f * g * sqrtf(g) + EPS_F);
    float alpha = *alpha_p;
    float beta  = *beta_p;
    float kappa = alpha * fabsf(K) + beta * fabsf(Hc);

    out[tid]            = K;
    out[NTOT + tid]     = Hc;
    out[2 * NTOT + tid] = kappa;
}

extern "C" void kernel_launch(void* const* d_in, const int* in_sizes, int n_in,
                              void* d_out, int out_size, void* d_ws, size_t ws_size,
                              hipStream_t stream) {
    const float* x       = (const float*)d_in[0];
    const float* alpha_p = (const float*)d_in[1];
    const float* beta_p  = (const float*)d_in[2];
    float* out = (float*)d_out;
    float* mws = (float*)d_ws;   // 8 MiB mean map

    // Kernel 1: NTOT/4 = 524288 threads
    mean64_kernel<<<(NTOT / 4) / 256, 256, 0, stream>>>(x, mws);
    // Kernel 2: NTOT threads
    curv_kernel<<<NTOT / 256, 256, 0, stream>>>(mws, alpha_p, beta_p, out);
}

// Round 3
// 99.991 us; speedup vs baseline: 1.1077x; 1.1077x over previous
//
#include <hip/hip_runtime.h>
#include <math.h>

#define N_IMG   8
#define C_CH    64
#define H_DIM   512
#define W_DIM   512
#define HW      (H_DIM * W_DIM)          // 262144
#define NTOT    (N_IMG * HW)             // 2097152
#define HW4     (HW / 4)                 // 65536 float4 per image plane
#define EPS_F   1e-8f

typedef float floatx4 __attribute__((ext_vector_type(4)));

// Kernel 1: mean over 64 channels. One thread per 4 consecutive pixels.
// Chunked unroll (16 loads in flight) + launch_bounds cap -> high occupancy;
// nontemporal loads keep the 512 MiB stream from thrashing L2 (mean map is
// reused by kernel 2 and should stay cached).
__global__ __launch_bounds__(256, 4) void mean64_kernel(const float* __restrict__ x,
                                                        float* __restrict__ m) {
    int o4 = blockIdx.x * blockDim.x + threadIdx.x;   // float4 index, [0, NTOT/4)
    int n  = o4 >> 16;                                // /HW4
    int s4 = o4 & (HW4 - 1);
    const floatx4* base = reinterpret_cast<const floatx4*>(x)
                        + (size_t)n * C_CH * HW4 + s4;
    float ax = 0.f, ay = 0.f, az = 0.f, aw = 0.f;
    for (int cc = 0; cc < C_CH; cc += 16) {
        #pragma unroll
        for (int c = 0; c < 16; ++c) {
            floatx4 v = __builtin_nontemporal_load(base + (size_t)(cc + c) * HW4);
            ax += v.x; ay += v.y; az += v.z; aw += v.w;
        }
    }
    const float inv = 1.0f / 64.0f;
    floatx4 r; r.x = ax * inv; r.y = ay * inv; r.z = az * inv; r.w = aw * inv;
    reinterpret_cast<floatx4*>(m)[o4] = r;
}

// Kernel 2: 3x3 clamped stencil + curvature math. One thread per pixel.
__global__ __launch_bounds__(256) void curv_kernel(const float* __restrict__ m,
                                                   const float* __restrict__ alpha_p,
                                                   const float* __restrict__ beta_p,
                                                   float* __restrict__ out) {
    int tid = blockIdx.x * blockDim.x + threadIdx.x;  // [0, NTOT)
    int n = tid >> 18;                                // /HW
    int s = tid & (HW - 1);
    int h = s >> 9;
    int w = s & (W_DIM - 1);
    const float* mp = m + (size_t)n * HW;

    int r0 = (h > 0) ? h - 1 : 0;
    int r2 = (h < H_DIM - 1) ? h + 1 : H_DIM - 1;
    int c0 = (w > 0) ? w - 1 : 0;
    int c2 = (w < W_DIM - 1) ? w + 1 : W_DIM - 1;

    const float* row0 = mp + r0 * W_DIM;
    const float* row1 = mp + h  * W_DIM;
    const float* row2 = mp + r2 * W_DIM;

    float m00 = row0[c0], m01 = row0[w], m02 = row0[c2];
    float m10 = row1[c0], m11 = row1[w], m12 = row1[c2];
    float m20 = row2[c0], m21 = row2[w], m22 = row2[c2];

    // d = [-.5,0,.5], s = [.25,.5,.25], d2 = [1,-2,1]; cross-correlation (no flip)
    float Ix  = 0.5f  * (0.25f * (m02 - m00) + 0.5f * (m12 - m10) + 0.25f * (m22 - m20));
    float Iy  = 0.5f  * (0.25f * (m20 - m00) + 0.5f * (m21 - m01) + 0.25f * (m22 - m02));
    float Ixx = 0.25f * (m00 - 2.0f * m01 + m02)
              + 0.5f  * (m10 - 2.0f * m11 + m12)
              + 0.25f * (m20 - 2.0f * m21 + m22);
    float Iyy = 0.25f * (m00 - 2.0f * m10 + m20)
              + 0.5f  * (m01 - 2.0f * m11 + m21)
              + 0.25f * (m02 - 2.0f * m12 + m22);
    float Ixy = 0.25f * (m00 - m02 - m20 + m22);

    float ix2 = Ix * Ix, iy2 = Iy * Iy;
    float g = 1.0f + ix2 + iy2;
    float K = (Ixx * Iyy - Ixy * Ixy) / (g * g + EPS_F);
    float Hc = ((1.0f + ix2) * Iyy - 2.0f * Ix * Iy * Ixy + (1.0f + iy2) * Ixx)
             / (2.0f * g * sqrtf(g) + EPS_F);
    float alpha = *alpha_p;
    float beta  = *beta_p;
    float kappa = alpha * fabsf(K) + beta * fabsf(Hc);

    out[tid]            = K;
    out[NTOT + tid]     = Hc;
    out[2 * NTOT + tid] = kappa;
}

extern "C" void kernel_launch(void* const* d_in, const int* in_sizes, int n_in,
                              void* d_out, int out_size, void* d_ws, size_t ws_size,
                              hipStream_t stream) {
    const float* x       = (const float*)d_in[0];
    const float* alpha_p = (const float*)d_in[1];
    const float* beta_p  = (const float*)d_in[2];
    float* out = (float*)d_out;
    float* mws = (float*)d_ws;   // 8 MiB mean map

    // Kernel 1: NTOT/4 = 524288 threads
    mean64_kernel<<<(NTOT / 4) / 256, 256, 0, stream>>>(x, mws);
    // Kernel 2: NTOT threads
    curv_kernel<<<NTOT / 256, 256, 0, stream>>>(mws, alpha_p, beta_p, out);
}

// Round 4
// 97.709 us; speedup vs baseline: 1.1336x; 1.0234x over previous
//
#include <hip/hip_runtime.h>
#include <math.h>

#define N_IMG   8
#define C_CH    64
#define H_DIM   512
#define W_DIM   512
#define HW      (H_DIM * W_DIM)          // 262144
#define NTOT    (N_IMG * HW)             // 2097152
#define HW4     (HW / 4)                 // 65536 float4 per image plane
#define EPS_F   1e-8f

typedef float floatx4 __attribute__((ext_vector_type(4)));

// Kernel 1: mean over 64 channels.
// Each block owns 1024 consecutive quads (16 KB per channel) => the memory
// controllers see 16 KB sequential bursts per channel visit instead of 4 KB,
// reducing DRAM row activates. Each thread accumulates 4 quads (j-strided by
// 256 = blockDim) over 64 channels, chunked 4 channels at a time:
// 16 NT loads in flight (64 VGPRs) + 16 accumulators, fits __launch_bounds__(256,4).
__global__ __launch_bounds__(256, 4) void mean64_kernel(const float* __restrict__ x,
                                                        float* __restrict__ m) {
    int bq  = blockIdx.x << 10;            // quad base, 1024 quads per block
    int n   = bq >> 16;                    // image index (1024 | 65536, no spanning)
    int s4b = bq & (HW4 - 1);
    int t   = threadIdx.x;
    const floatx4* base = reinterpret_cast<const floatx4*>(x)
                        + (size_t)n * C_CH * HW4 + s4b + t;

    floatx4 acc0 = {0,0,0,0}, acc1 = {0,0,0,0}, acc2 = {0,0,0,0}, acc3 = {0,0,0,0};

    for (int cc = 0; cc < C_CH; cc += 4) {
        floatx4 v[4][4];
        #pragma unroll
        for (int c = 0; c < 4; ++c) {
            const floatx4* p = base + (size_t)(cc + c) * HW4;
            #pragma unroll
            for (int j = 0; j < 4; ++j)
                v[c][j] = __builtin_nontemporal_load(p + (j << 8));
        }
        #pragma unroll
        for (int c = 0; c < 4; ++c) {
            acc0 += v[c][0];
            acc1 += v[c][1];
            acc2 += v[c][2];
            acc3 += v[c][3];
        }
    }
    const float inv = 1.0f / 64.0f;
    floatx4* mo = reinterpret_cast<floatx4*>(m) + bq + t;
    mo[0]   = acc0 * inv;
    mo[256] = acc1 * inv;
    mo[512] = acc2 * inv;
    mo[768] = acc3 * inv;
}

// Kernel 2: 3x3 clamped stencil + curvature math. One thread per pixel.
__global__ __launch_bounds__(256) void curv_kernel(const float* __restrict__ m,
                                                   const float* __restrict__ alpha_p,
                                                   const float* __restrict__ beta_p,
                                                   float* __restrict__ out) {
    int tid = blockIdx.x * blockDim.x + threadIdx.x;  // [0, NTOT)
    int n = tid >> 18;                                // /HW
    int s = tid & (HW - 1);
    int h = s >> 9;
    int w = s & (W_DIM - 1);
    const float* mp = m + (size_t)n * HW;

    int r0 = (h > 0) ? h - 1 : 0;
    int r2 = (h < H_DIM - 1) ? h + 1 : H_DIM - 1;
    int c0 = (w > 0) ? w - 1 : 0;
    int c2 = (w < W_DIM - 1) ? w + 1 : W_DIM - 1;

    const float* row0 = mp + r0 * W_DIM;
    const float* row1 = mp + h  * W_DIM;
    const float* row2 = mp + r2 * W_DIM;

    float m00 = row0[c0], m01 = row0[w], m02 = row0[c2];
    float m10 = row1[c0], m11 = row1[w], m12 = row1[c2];
    float m20 = row2[c0], m21 = row2[w], m22 = row2[c2];

    // d = [-.5,0,.5], s = [.25,.5,.25], d2 = [1,-2,1]; cross-correlation (no flip)
    float Ix  = 0.5f  * (0.25f * (m02 - m00) + 0.5f * (m12 - m10) + 0.25f * (m22 - m20));
    float Iy  = 0.5f  * (0.25f * (m20 - m00) + 0.5f * (m21 - m01) + 0.25f * (m22 - m02));
    float Ixx = 0.25f * (m00 - 2.0f * m01 + m02)
              + 0.5f  * (m10 - 2.0f * m11 + m12)
              + 0.25f * (m20 - 2.0f * m21 + m22);
    float Iyy = 0.25f * (m00 - 2.0f * m10 + m20)
              + 0.5f  * (m01 - 2.0f * m11 + m21)
              + 0.25f * (m02 - 2.0f * m12 + m22);
    float Ixy = 0.25f * (m00 - m02 - m20 + m22);

    float ix2 = Ix * Ix, iy2 = Iy * Iy;
    float g = 1.0f + ix2 + iy2;
    float K = (Ixx * Iyy - Ixy * Ixy) / (g * g + EPS_F);
    float Hc = ((1.0f + ix2) * Iyy - 2.0f * Ix * Iy * Ixy + (1.0f + iy2) * Ixx)
             / (2.0f * g * sqrtf(g) + EPS_F);
    float alpha = *alpha_p;
    float beta  = *beta_p;
    float kappa = alpha * fabsf(K) + beta * fabsf(Hc);

    __builtin_nontemporal_store(K,     out + tid);
    __builtin_nontemporal_store(Hc,    out + NTOT + tid);
    __builtin_nontemporal_store(kappa, out + 2 * NTOT + tid);
}

extern "C" void kernel_launch(void* const* d_in, const int* in_sizes, int n_in,
                              void* d_out, int out_size, void* d_ws, size_t ws_size,
                              hipStream_t stream) {
    const float* x       = (const float*)d_in[0];
    const float* alpha_p = (const float*)d_in[1];
    const float* beta_p  = (const float*)d_in[2];
    float* out = (float*)d_out;
    float* mws = (float*)d_ws;   // 8 MiB mean map

    // Kernel 1: 512 blocks x 256 threads, 1024 quads per block
    mean64_kernel<<<(NTOT / 4) / 1024, 256, 0, stream>>>(x, mws);
    // Kernel 2: NTOT threads
    curv_kernel<<<NTOT / 256, 256, 0, stream>>>(mws, alpha_p, beta_p, out);
}